// Round 1
// baseline (368.348 us; speedup 1.0000x reference)
//
#include <hip/hip_runtime.h>

// Problem constants
static constexpr int   Cc  = 21;
static constexpr int   HWn = 512 * 512;         // 262144 = 2^18
static constexpr int   Nn  = 8 * HWn;           // 2097152 pixels
static constexpr float MAXM  = 0.5f;
static constexpr float Sc    = 30.0f;
static constexpr float LOG2E = 1.4426950408889634f;
static constexpr float LN2   = 0.6931471805599453f;

static constexpr int HIST_BLOCKS = 256;               // 256 blk * 256 thr * 8 int4 = Nn/4
static constexpr int LOSS_BLOCKS = Nn / 4 / 256;      // 2048

// ws layout (bytes): 0: int counts[21] ; 96: uint done-flag ; 128: double partial[2048]
static constexpr int WS_COUNTS = 0;
static constexpr int WS_FLAG   = 96;
static constexpr int WS_PART   = 128;

// ---------------------------------------------------------------------------
// K1: class histogram. 256 blocks grid-stride (8 int4 per thread), LDS-local
// atomics, then only 21 global atomics per block (256-deep contention per
// address instead of 2048-deep).
__global__ __launch_bounds__(256) void hist_kernel(const int4* __restrict__ t4,
                                                   int* __restrict__ counts) {
    __shared__ int lh[Cc];
    int t = threadIdx.x;
    if (t < Cc) lh[t] = 0;
    __syncthreads();
    int base = blockIdx.x * (256 * 8) + t;
    #pragma unroll
    for (int i = 0; i < 8; ++i) {
        int4 v = t4[base + i * 256];
        atomicAdd(&lh[v.x], 1);
        atomicAdd(&lh[v.y], 1);
        atomicAdd(&lh[v.z], 1);
        atomicAdd(&lh[v.w], 1);
    }
    __syncthreads();
    if (t < Cc) atomicAdd(&counts[t], lh[t]);
}

// ---------------------------------------------------------------------------
// K2: main loss, with m_list computation fused into the first wave (counts
// are 84 L2-hot bytes; every block recomputes in ~100 cycles) and the final
// mean fused in via the fenced last-block-done pattern. Per-block result is
// a PLAIN store to partial[blockIdx] — zero contended atomics on the hot path.
//
// Core structure unchanged from the verified kernel: four pixels per thread
// via float4 loads across the 21-class stride; x[21] float4 = 84 data VGPRs;
// pass 2 recomputes the margin-adjusted value (no second array -> no spill).
// Softmax in base-2 domain: one v_exp per element, single *LN2 at the end.
__global__ __launch_bounds__(256, 2) void loss_kernel(const float* __restrict__ pred,
                                                      const int4* __restrict__ t4,
                                                      const int* __restrict__ counts,
                                                      double* __restrict__ partial,
                                                      unsigned int* __restrict__ flag,
                                                      float* __restrict__ out) {
    __shared__ float  s_sm[Cc];
    __shared__ double wsum[4];
    __shared__ bool   s_last;
    int t = threadIdx.x;

    int tid = blockIdx.x * 256 + t;           // tid in [0, Nn/4)
    int n0  = tid * 4;
    int b   = n0 >> 18;                       // HWn = 2^18
    int hw  = n0 & (HWn - 1);
    const float4* p4 = (const float4*)(pred + (size_t)b * Cc * HWn + hw);

    // issue all 21 coalesced float4 loads back-to-back (MLP) — independent of
    // the m_list computation below, so they fly while wave 0 does scalar work
    float4 x[Cc];
    #pragma unroll
    for (int c = 0; c < Cc; ++c) x[c] = p4[(size_t)c * (HWn / 4)];

    int4 y4 = t4[tid];

    // fused m_list: wave 0 computes sm[c] = S*log2e * m_list[c]
    if (t < 64) {
        float mval = 0.0f;
        if (t < Cc) {
            float cnt = (float)counts[t] + 1e-4f;
            mval = 1.0f / sqrtf(sqrtf(cnt));  // x^-0.25
        }
        float mx = mval;
        #pragma unroll
        for (int o = 32; o >= 1; o >>= 1) mx = fmaxf(mx, __shfl_down(mx, o));
        mx = __shfl(mx, 0);
        if (t < Cc) s_sm[t] = Sc * LOG2E * mval * (MAXM / mx);
    }
    __syncthreads();

    int ys[4] = {y4.x, y4.y, y4.z, y4.w};
    float smy[4];
    #pragma unroll
    for (int k = 0; k < 4; ++k) smy[k] = s_sm[ys[k]];

    const float S2 = Sc * LOG2E;

    // pass 1: max + target value (base-2 logits), nothing stored
    float mx[4] = {-1e30f, -1e30f, -1e30f, -1e30f};
    float vy[4] = {0.f, 0.f, 0.f, 0.f};
    #pragma unroll
    for (int c = 0; c < Cc; ++c) {
        float xs[4] = {x[c].x, x[c].y, x[c].z, x[c].w};
        #pragma unroll
        for (int k = 0; k < 4; ++k) {
            bool  isy = (c == ys[k]);
            float val = fmaf(S2, xs[k], isy ? -smy[k] : 0.0f);
            mx[k] = fmaxf(mx[k], val);
            vy[k] = isy ? val : vy[k];
        }
    }

    // pass 2: sum of exp2 recomputed from x
    float nll2 = 0.0f;
    #pragma unroll
    for (int k = 0; k < 4; ++k) {
        float cb = -mx[k];                    // non-target: val - mx
        float cy = -smy[k] - mx[k];           // target: val - mx
        float sum = 0.0f;
        #pragma unroll
        for (int c = 0; c < Cc; ++c) {
            float xs = (k == 0) ? x[c].x : (k == 1) ? x[c].y : (k == 2) ? x[c].z : x[c].w;
            sum += exp2f(fmaf(S2, xs, (c == ys[k]) ? cy : cb));
        }
        nll2 += __log2f(sum) + mx[k] - vy[k];
    }
    float nll = nll2 * LN2;

    // wave (64-lane) reduce
    #pragma unroll
    for (int o = 32; o >= 1; o >>= 1) nll += __shfl_down(nll, o);

    int wave = t >> 6;
    int lane = t & 63;
    if (lane == 0) wsum[wave] = (double)nll;
    __syncthreads();
    if (t == 0) {
        double bsum = wsum[0] + wsum[1] + wsum[2] + wsum[3];
        partial[blockIdx.x] = bsum;           // plain store, no contention
        __threadfence();                      // release partial before flag bump
        unsigned done = atomicAdd(flag, 1u);
        s_last = (done == (unsigned)(LOSS_BLOCKS - 1));
    }
    __syncthreads();

    if (s_last) {
        __threadfence();                      // acquire other blocks' partials
        double s = 0.0;
        for (int i = t; i < LOSS_BLOCKS; i += 256) s += partial[i];
        #pragma unroll
        for (int o = 32; o >= 1; o >>= 1) s += __shfl_down(s, o);
        if ((t & 63) == 0) wsum[t >> 6] = s;
        __syncthreads();
        if (t == 0)
            out[0] = (float)((wsum[0] + wsum[1] + wsum[2] + wsum[3]) / (double)Nn);
    }
}

extern "C" void kernel_launch(void* const* d_in, const int* in_sizes, int n_in,
                              void* d_out, int out_size, void* d_ws, size_t ws_size,
                              hipStream_t stream) {
    const float* pred   = (const float*)d_in[0];
    const int*   target = (const int*)d_in[1];
    float*       out    = (float*)d_out;

    char* ws = (char*)d_ws;
    int*          counts  = (int*)(ws + WS_COUNTS);
    unsigned int* flag    = (unsigned int*)(ws + WS_FLAG);
    double*       partial = (double*)(ws + WS_PART);

    hipMemsetAsync(d_ws, 0, 128, stream);     // zero counts + done-flag

    hist_kernel <<<HIST_BLOCKS, 256, 0, stream>>>((const int4*)target, counts);
    loss_kernel <<<LOSS_BLOCKS, 256, 0, stream>>>(pred, (const int4*)target,
                                                  counts, partial, flag, out);
}

// Round 2
// 339.930 us; speedup vs baseline: 1.0836x; 1.0836x over previous
//
#include <hip/hip_runtime.h>

// Problem constants
static constexpr int   Cc  = 21;
static constexpr int   HWn = 512 * 512;         // 262144 = 2^18
static constexpr int   Nn  = 8 * HWn;           // 2097152 pixels
static constexpr float MAXM  = 0.5f;
static constexpr float Sc    = 30.0f;
static constexpr float LOG2E = 1.4426950408889634f;
static constexpr float LN2   = 0.6931471805599453f;

static constexpr int HIST_BLOCKS = 512;               // 512 blk * 256 thr * 4 int4 = Nn/4
static constexpr int LOSS_BLOCKS = Nn / 4 / 256;      // 2048

// ws layout (bytes): 0: int counts[21] ; 96: uint done-flag ; 128: double partial[2048]
static constexpr int WS_COUNTS = 0;
static constexpr int WS_FLAG   = 96;
static constexpr int WS_PART   = 128;

// ---------------------------------------------------------------------------
// K1: class histogram. 512 blocks (4 int4 per thread). Per-WAVE LDS
// sub-histograms cut same-address LDS atomic serialization 4x; then 21
// global atomics per block (512-deep per address — negligible).
__global__ __launch_bounds__(256) void hist_kernel(const int4* __restrict__ t4,
                                                   int* __restrict__ counts) {
    __shared__ int lh[4][Cc];
    int t = threadIdx.x;
    if (t < 4 * Cc) ((int*)lh)[t] = 0;
    __syncthreads();
    int wave = t >> 6;
    int base = blockIdx.x * (256 * 4) + t;
    #pragma unroll
    for (int i = 0; i < 4; ++i) {
        int4 v = t4[base + i * 256];
        atomicAdd(&lh[wave][v.x], 1);
        atomicAdd(&lh[wave][v.y], 1);
        atomicAdd(&lh[wave][v.z], 1);
        atomicAdd(&lh[wave][v.w], 1);
    }
    __syncthreads();
    if (t < Cc)
        atomicAdd(&counts[t], lh[0][t] + lh[1][t] + lh[2][t] + lh[3][t]);
}

// ---------------------------------------------------------------------------
// K2: main loss — ONE-PASS online softmax. No x[21] register tile (round-1's
// two-pass variant lost it to remat: VGPR=60, 190us). Per pixel only
// (m, s, vy) live: s = s*exp2(m - mn) + exp2(val - mn). Base-2 domain
// throughout; single *LN2 at the end. m_list recomputed per-wave from
// L2-hot counts via shuffles (no LDS, no barrier before the hot loop).
// Per-block result is a PLAIN store; final mean via fenced last-block-done.
__global__ __launch_bounds__(256, 4) void loss_kernel(const float* __restrict__ pred,
                                                      const int4* __restrict__ t4,
                                                      const int* __restrict__ counts,
                                                      double* __restrict__ partial,
                                                      unsigned int* __restrict__ flag,
                                                      float* __restrict__ out) {
    __shared__ double wsum[4];
    __shared__ bool   s_last;
    int t    = threadIdx.x;
    int lane = t & 63;

    // per-wave m_list: sm = S*log2e * m_list[c] held in lane c (c < 21)
    float mval = 0.0f;
    if (lane < Cc) {
        float cnt = (float)counts[lane] + 1e-4f;
        mval = 1.0f / sqrtf(sqrtf(cnt));      // x^-0.25, same expr as reference
    }
    float mxm = mval;
    #pragma unroll
    for (int o = 32; o >= 1; o >>= 1) mxm = fmaxf(mxm, __shfl_down(mxm, o));
    mxm = __shfl(mxm, 0);
    float smv = Sc * LOG2E * mval * (MAXM / mxm);

    int tid = blockIdx.x * 256 + t;           // tid in [0, Nn/4)
    int n0  = tid * 4;
    int b   = n0 >> 18;                       // HWn = 2^18
    int hw  = n0 & (HWn - 1);
    const float4* p4 = (const float4*)(pred + (size_t)b * Cc * HWn + hw);

    int4 y4 = t4[tid];
    int ys[4] = {y4.x, y4.y, y4.z, y4.w};
    float smy[4];
    #pragma unroll
    for (int k = 0; k < 4; ++k) smy[k] = __shfl(smv, ys[k]);

    const float S2 = Sc * LOG2E;
    float m[4], s[4], vy[4];
    #pragma unroll
    for (int k = 0; k < 4; ++k) { m[k] = -1e30f; s[k] = 0.0f; vy[k] = 0.0f; }

    // one pass: online max + rescaled exp2-sum; loads pipeline freely since
    // each float4 is consumed exactly once (no remat incentive).
    #pragma unroll
    for (int c = 0; c < Cc; ++c) {
        float4 xc = p4[(size_t)c * (HWn / 4)];
        float xs[4] = {xc.x, xc.y, xc.z, xc.w};
        #pragma unroll
        for (int k = 0; k < 4; ++k) {
            bool  isy = (c == ys[k]);
            float val = fmaf(S2, xs[k], isy ? -smy[k] : 0.0f);
            float mn  = fmaxf(m[k], val);
            s[k]  = fmaf(s[k], exp2f(m[k] - mn), exp2f(val - mn));
            m[k]  = mn;
            vy[k] = isy ? val : vy[k];
        }
    }

    float nll = 0.0f;
    #pragma unroll
    for (int k = 0; k < 4; ++k) nll += __log2f(s[k]) + m[k] - vy[k];
    nll *= LN2;

    // wave (64-lane) reduce
    #pragma unroll
    for (int o = 32; o >= 1; o >>= 1) nll += __shfl_down(nll, o);

    int wave = t >> 6;
    if ((t & 63) == 0) wsum[wave] = (double)nll;
    __syncthreads();
    if (t == 0) {
        double bsum = wsum[0] + wsum[1] + wsum[2] + wsum[3];
        partial[blockIdx.x] = bsum;           // plain store, no contention
        __threadfence();                      // release partial before flag bump
        unsigned done = atomicAdd(flag, 1u);
        s_last = (done == (unsigned)(LOSS_BLOCKS - 1));
    }
    __syncthreads();

    if (s_last) {
        __threadfence();                      // acquire other blocks' partials
        double sm = 0.0;
        for (int i = t; i < LOSS_BLOCKS; i += 256) sm += partial[i];
        #pragma unroll
        for (int o = 32; o >= 1; o >>= 1) sm += __shfl_down(sm, o);
        if ((t & 63) == 0) wsum[t >> 6] = sm;
        __syncthreads();
        if (t == 0)
            out[0] = (float)((wsum[0] + wsum[1] + wsum[2] + wsum[3]) / (double)Nn);
    }
}

extern "C" void kernel_launch(void* const* d_in, const int* in_sizes, int n_in,
                              void* d_out, int out_size, void* d_ws, size_t ws_size,
                              hipStream_t stream) {
    const float* pred   = (const float*)d_in[0];
    const int*   target = (const int*)d_in[1];
    float*       out    = (float*)d_out;

    char* ws = (char*)d_ws;
    int*          counts  = (int*)(ws + WS_COUNTS);
    unsigned int* flag    = (unsigned int*)(ws + WS_FLAG);
    double*       partial = (double*)(ws + WS_PART);

    hipMemsetAsync(d_ws, 0, 128, stream);     // zero counts + done-flag

    hist_kernel <<<HIST_BLOCKS, 256, 0, stream>>>((const int4*)target, counts);
    loss_kernel <<<LOSS_BLOCKS, 256, 0, stream>>>(pred, (const int4*)target,
                                                  counts, partial, flag, out);
}